// Round 1
// baseline (22480.470 us; speedup 1.0000x reference)
//
#include <hip/hip_runtime.h>
#include <hip/hip_bf16.h>
#include <cstddef>

typedef __attribute__((ext_vector_type(8))) short bf16x8;
typedef __attribute__((ext_vector_type(4))) float f32x4;

constexpr int kB = 64;      // batch
constexpr int kS = 1024;    // seq len
constexpr int kH = 512;     // hidden (== input size)
constexpr int kNWGL = 128;  // workgroups per layer
constexpr int kUPW = 4;     // hidden units per workgroup (12 gate rows)

__device__ __forceinline__ unsigned short f2bf(float f) {
  unsigned int u = __float_as_uint(f);
  u += 0x7FFFu + ((u >> 16) & 1u);   // round-to-nearest-even
  return (unsigned short)(u >> 16);
}

// fp32 -> bf16 bulk convert, 4 elems/thread
__global__ void cvt_f32_bf16(const float* __restrict__ in,
                             unsigned short* __restrict__ out, int n4) {
  int i = blockIdx.x * blockDim.x + threadIdx.x;
  if (i >= n4) return;
  float4 v = ((const float4*)in)[i];
  ushort4 o;
  o.x = f2bf(v.x); o.y = f2bf(v.y); o.z = f2bf(v.z); o.w = f2bf(v.w);
  ((ushort4*)out)[i] = o;
}

// Fused 2-layer GRU. blocks 0..127 = layer 0, 128..255 = layer 1.
// Each WG owns kUPW hidden units (all 3 gates). Weights live in registers
// as MFMA B-fragments. Per step: fused input GEMM + recurrent GEMM
// (16x16x32 bf16 MFMA, one 16-batch M-tile per wave), gate math in fp32,
// publish h via bf16 broadcast buffer + device-scope counter.
__launch_bounds__(256, 1)
__global__ void gru_fused(const unsigned short* __restrict__ xbf,   // [B][S][H]
                          const unsigned short* __restrict__ wih0,  // [3H][H]
                          const unsigned short* __restrict__ whh0,
                          const unsigned short* __restrict__ wih1,
                          const unsigned short* __restrict__ whh1,
                          const float* __restrict__ bih0, const float* __restrict__ bhh0,
                          const float* __restrict__ bih1, const float* __restrict__ bhh1,
                          unsigned short* __restrict__ hs0,    // [S*B][H] bf16
                          unsigned short* __restrict__ h1buf,  // [2][B][H] bf16
                          const unsigned short* __restrict__ hz, // zeros [B][H]
                          unsigned int* __restrict__ cnt0,
                          unsigned int* __restrict__ cnt1,
                          float* __restrict__ out) {
  const int tid  = threadIdx.x;
  const int lane = tid & 63;
  const int wv   = tid >> 6;            // wave 0..3
  const int layer = blockIdx.x >> 7;
  const int wg    = blockIdx.x & (kNWGL - 1);
  const int j0    = wg * kUPW;

  const unsigned short* wih = layer ? wih1 : wih0;
  const unsigned short* whh = layer ? whh1 : whh0;
  const float* bih = layer ? bih1 : bih0;
  const float* bhh = layer ? bhh1 : bhh0;

  // ---- B-fragments (weights) in registers, loaded once ----
  // B[k][n] = w[orig(n)][k]; lane holds col n=lane&15, k = kk*32 + (lane>>4)*8 + j
  bf16x8 bx[16], bh[16];
  {
    const int n = lane & 15, hi = lane >> 4;
    if (n < 12) {
      const int orig = (n >> 2) * kH + j0 + (n & 3);  // gate*512 + unit
      const unsigned short* pX = wih + (size_t)orig * kH + hi * 8;
      const unsigned short* pH = whh + (size_t)orig * kH + hi * 8;
#pragma unroll
      for (int kk = 0; kk < 16; ++kk) {
        bx[kk] = *(const bf16x8*)(pX + kk * 32);
        bh[kk] = *(const bf16x8*)(pH + kk * 32);
      }
    } else {
      bf16x8 z = {0, 0, 0, 0, 0, 0, 0, 0};
#pragma unroll
      for (int kk = 0; kk < 16; ++kk) { bx[kk] = z; bh[kk] = z; }
    }
  }

  // gate-phase assignment: thread -> (batch gb, unit gu)
  const int gb = tid & 63;
  const int gu = wv;
  const float bihr = bih[j0 + gu], bihz = bih[kH + j0 + gu], bihn = bih[2 * kH + j0 + gu];
  const float bhhr = bhh[j0 + gu], bhhz = bhh[kH + j0 + gu], bhhn = bhh[2 * kH + j0 + gu];
  float hprev = 0.0f;  // fp32 master state for (gb, j0+gu)

  __shared__ float gxl[64][16];
  __shared__ float ghl[64][16];
  __shared__ unsigned short hl[64][4];
  __shared__ float hlf[64][4];

  const int b0   = wv * 16;             // M-tile batch base for this wave
  const int arow = b0 + (lane & 15);    // A row = batch
  const int ahi  = (lane >> 4) * 8;     // k sub-offset

  unsigned int* mycnt = layer ? cnt1 : cnt0;

  for (int t = 0; t < kS; ++t) {
    // ---- wait for inputs of this step ----
    if (tid == 0) {
      if (layer == 0) {
        if (t > 0)
          while (__hip_atomic_load(cnt0 + (t - 1), __ATOMIC_RELAXED,
                                   __HIP_MEMORY_SCOPE_AGENT) < (unsigned)kNWGL)
            __builtin_amdgcn_s_sleep(1);
      } else {
        while (__hip_atomic_load(cnt0 + t, __ATOMIC_RELAXED,
                                 __HIP_MEMORY_SCOPE_AGENT) < (unsigned)kNWGL)
          __builtin_amdgcn_s_sleep(1);
        if (t > 0)
          while (__hip_atomic_load(cnt1 + (t - 1), __ATOMIC_RELAXED,
                                   __HIP_MEMORY_SCOPE_AGENT) < (unsigned)kNWGL)
            __builtin_amdgcn_s_sleep(1);
      }
      __threadfence();  // acquire: invalidate L1 + XCD L2 before reads
    }
    __syncthreads();

    // ---- A-operand row pointers for this lane ----
    const unsigned short* pAX;
    if (layer == 0) pAX = xbf + ((size_t)arow * kS + t) * kH + ahi;
    else            pAX = hs0 + ((size_t)t * kB + arow) * kH + ahi;
    const unsigned short* pAH;
    if (t == 0)          pAH = hz + (size_t)arow * kH + ahi;
    else if (layer == 0) pAH = hs0 + ((size_t)(t - 1) * kB + arow) * kH + ahi;
    else                 pAH = h1buf + ((size_t)((t - 1) & 1) * kB * kH) + (size_t)arow * kH + ahi;

    // ---- two fused GEMMs: gx = in_t @ Wihᵀ, gh = h_{t-1} @ Whhᵀ ----
    f32x4 accx = {0.f, 0.f, 0.f, 0.f};
    f32x4 acch = {0.f, 0.f, 0.f, 0.f};
#pragma unroll
    for (int kk = 0; kk < 16; ++kk) {
      bf16x8 ax = *(const bf16x8*)(pAX + kk * 32);
      bf16x8 ah = *(const bf16x8*)(pAH + kk * 32);
      accx = __builtin_amdgcn_mfma_f32_16x16x32_bf16(ax, bx[kk], accx, 0, 0, 0);
      acch = __builtin_amdgcn_mfma_f32_16x16x32_bf16(ah, bh[kk], acch, 0, 0, 0);
    }

    // ---- exchange via LDS: C[m][n] -> [batch][gate-row] ----
    {
      const int n = lane & 15, mb = b0 + (lane >> 4) * 4;
#pragma unroll
      for (int r = 0; r < 4; ++r) {
        gxl[mb + r][n] = accx[r];
        ghl[mb + r][n] = acch[r];
      }
    }
    __syncthreads();

    // ---- gate math (fp32) ----
    {
      const float xr = gxl[gb][gu]     + bihr;
      const float xz = gxl[gb][4 + gu] + bihz;
      const float xn = gxl[gb][8 + gu] + bihn;
      const float hr = ghl[gb][gu]     + bhhr;
      const float hzv = ghl[gb][4 + gu] + bhhz;
      const float hn = ghl[gb][8 + gu] + bhhn;
      const float r = 1.0f / (1.0f + __expf(-(xr + hr)));
      const float z = 1.0f / (1.0f + __expf(-(xz + hzv)));
      const float nn = tanhf(xn + r * hn);
      const float hnew = (1.0f - z) * nn + z * hprev;
      hprev = hnew;
      hl[gb][gu] = f2bf(hnew);
      if (layer) hlf[gb][gu] = hnew;
      if (t == kS - 1)  // h_n epilogue
        out[(size_t)kB * kS * kH + (size_t)layer * kB * kH + (size_t)gb * kH + j0 + gu] = hnew;
    }
    __syncthreads();

    // ---- publish h (packed 8B bf16), layer1 also writes output fp32 ----
    if (tid < 64) {
      unsigned long long pk = *(const unsigned long long*)&hl[tid][0];
      if (layer == 0) {
        *(unsigned long long*)(hs0 + ((size_t)t * kB + tid) * kH + j0) = pk;
      } else {
        *(unsigned long long*)(h1buf + ((size_t)(t & 1) * kB * kH) + (size_t)tid * kH + j0) = pk;
        float4 o4 = *(const float4*)&hlf[tid][0];
        *(float4*)(out + ((size_t)tid * kS + t) * kH + j0) = o4;  // [b][t][h]
      }
    }
    __syncthreads();  // drains vmcnt per wave before the fence

    if (tid == 0) {
      __threadfence();  // release: write back dirty L2 before flag
      __hip_atomic_fetch_add(mycnt + t, 1u, __ATOMIC_RELEASE, __HIP_MEMORY_SCOPE_AGENT);
    }
  }
}

extern "C" void kernel_launch(void* const* d_in, const int* in_sizes, int n_in,
                              void* d_out, int out_size, void* d_ws, size_t ws_size,
                              hipStream_t stream) {
  const float* x     = (const float*)d_in[0];
  const float* w_ih0 = (const float*)d_in[1];
  const float* w_hh0 = (const float*)d_in[2];
  const float* b_ih0 = (const float*)d_in[3];
  const float* b_hh0 = (const float*)d_in[4];
  const float* w_ih1 = (const float*)d_in[5];
  const float* w_hh1 = (const float*)d_in[6];
  const float* b_ih1 = (const float*)d_in[7];
  const float* b_hh1 = (const float*)d_in[8];
  float* out = (float*)d_out;

  // ---- workspace layout (ushort elements unless noted) ----
  unsigned short* ws = (unsigned short*)d_ws;
  const size_t nX = (size_t)kB * kS * kH;   // 33,554,432
  const size_t nW = (size_t)3 * kH * kH;    // 786,432
  unsigned short* xbf   = ws;
  unsigned short* wih0b = xbf + nX;
  unsigned short* whh0b = wih0b + nW;
  unsigned short* wih1b = whh0b + nW;
  unsigned short* whh1b = wih1b + nW;
  unsigned short* hs0   = whh1b + nW;             // nX elems
  unsigned short* h1buf = hs0 + nX;               // 2*B*H
  unsigned short* hz    = h1buf + 2 * kB * kH;    // B*H
  unsigned int*   cnt0  = (unsigned int*)(hz + kB * kH);
  unsigned int*   cnt1  = cnt0 + kS;

  // zero hz + cnt0 + cnt1 (contiguous region) each launch for determinism
  size_t zero_bytes = (size_t)kB * kH * 2 + 2 * kS * sizeof(unsigned int);
  hipMemsetAsync((void*)hz, 0, zero_bytes, stream);

  // converts
  {
    int n4 = (int)(nX / 4);
    cvt_f32_bf16<<<n4 / 256, 256, 0, stream>>>(x, xbf, n4);
    int w4 = (int)(nW / 4);
    cvt_f32_bf16<<<w4 / 256, 256, 0, stream>>>(w_ih0, wih0b, w4);
    cvt_f32_bf16<<<w4 / 256, 256, 0, stream>>>(w_hh0, whh0b, w4);
    cvt_f32_bf16<<<w4 / 256, 256, 0, stream>>>(w_ih1, wih1b, w4);
    cvt_f32_bf16<<<w4 / 256, 256, 0, stream>>>(w_hh1, whh1b, w4);
  }

  // fused persistent GRU (cooperative: all 256 WGs must be co-resident)
  {
    const unsigned short* a_xbf = xbf;
    const unsigned short* a_wih0 = wih0b; const unsigned short* a_whh0 = whh0b;
    const unsigned short* a_wih1 = wih1b; const unsigned short* a_whh1 = whh1b;
    const unsigned short* a_hz = hz;
    unsigned short* a_hs0 = hs0; unsigned short* a_h1 = h1buf;
    unsigned int* a_c0 = cnt0; unsigned int* a_c1 = cnt1;
    float* a_out = out;
    void* args[] = {
        (void*)&a_xbf, (void*)&a_wih0, (void*)&a_whh0, (void*)&a_wih1, (void*)&a_whh1,
        (void*)&b_ih0, (void*)&b_hh0, (void*)&b_ih1, (void*)&b_hh1,
        (void*)&a_hs0, (void*)&a_h1, (void*)&a_hz, (void*)&a_c0, (void*)&a_c1,
        (void*)&a_out};
    hipLaunchCooperativeKernel((void*)gru_fused, dim3(2 * kNWGL), dim3(256),
                               args, 0, stream);
  }
}

// Round 5
// 9981.570 us; speedup vs baseline: 2.2522x; 2.2522x over previous
//
#include <hip/hip_runtime.h>
#include <hip/hip_bf16.h>
#include <cstddef>

typedef __attribute__((ext_vector_type(8))) short bf16x8;
typedef __attribute__((ext_vector_type(4))) float f32x4;

constexpr int kB = 64;      // batch
constexpr int kS = 1024;    // seq len
constexpr int kH = 512;     // hidden (== input size)
constexpr int kNWGL = 128;  // workgroups per layer
constexpr int kUPW = 4;     // hidden units per workgroup (12 gate rows)

__device__ __forceinline__ unsigned short f2bf(float f) {
  unsigned int u = __float_as_uint(f);
  u += 0x7FFFu + ((u >> 16) & 1u);   // round-to-nearest-even
  return (unsigned short)(u >> 16);
}

// ---------------- coherent (IF$-level) access helpers ----------------
// sc0 sc1 on load/store = system-scope: bypass L1 + non-coherent XCD L2,
// hit the Infinity-Cache coherence point directly. No wbl2/inv fences needed.

__device__ __forceinline__ void st_u32_coh(unsigned int* p, unsigned int v) {
  asm volatile("global_store_dword %0, %1, off sc0 sc1" ::"v"(p), "v"(v)
               : "memory");
}

__device__ __forceinline__ void st_u64_coh(void* p, unsigned long long v) {
  asm volatile("global_store_dwordx2 %0, %1, off sc0 sc1" ::"v"(p), "v"(v)
               : "memory");
}

// drain this wave's outstanding (write-through) stores, then set flag
__device__ __forceinline__ void st_flag_release(unsigned int* p, unsigned int v) {
  asm volatile("s_waitcnt vmcnt(0)\n\tglobal_store_dword %0, %1, off sc0 sc1"
               ::"v"(p), "v"(v) : "memory");
}

// one coherent 16B load at a literal byte offset from base p
#define COH_LD16(dst, p, OFF)                                             \
  asm volatile("global_load_dwordx4 %0, %1, off offset:" #OFF " sc0 sc1"  \
               : "=v"(dst) : "v"(p) : "memory")

// issue 16 coherent 16B loads (one 512-elem bf16 row as MFMA A-fragments)
__device__ __forceinline__ void coh_issue16(const unsigned short* p, bf16x8* d) {
  COH_LD16(d[0],  p, 0);
  COH_LD16(d[1],  p, 64);
  COH_LD16(d[2],  p, 128);
  COH_LD16(d[3],  p, 192);
  COH_LD16(d[4],  p, 256);
  COH_LD16(d[5],  p, 320);
  COH_LD16(d[6],  p, 384);
  COH_LD16(d[7],  p, 448);
  COH_LD16(d[8],  p, 512);
  COH_LD16(d[9],  p, 576);
  COH_LD16(d[10], p, 640);
  COH_LD16(d[11], p, 704);
  COH_LD16(d[12], p, 768);
  COH_LD16(d[13], p, 832);
  COH_LD16(d[14], p, 896);
  COH_LD16(d[15], p, 960);
}

__device__ __forceinline__ void wait_vm0(void) {
  asm volatile("s_waitcnt vmcnt(0)" ::: "memory");
  __builtin_amdgcn_sched_barrier(0);  // rule #18: stop MFMA hoisting past wait
}

// compiler-blessed agent-scope flag poll (proven on this chip in R1: agent
// relaxed loads observe IF$-resident updates and don't stick on stale L2)
__device__ __forceinline__ void spin_flag(const unsigned int* f) {
  while (__hip_atomic_load(f, __ATOMIC_RELAXED, __HIP_MEMORY_SCOPE_AGENT) == 0u)
    __builtin_amdgcn_s_sleep(1);
}

// ---------------- init: coherent zeros for flags + h0 ----------------
__global__ void init_coh(unsigned int* __restrict__ flags, int nflags,
                         unsigned int* __restrict__ hz32, int nhz32) {
  int i = blockIdx.x * blockDim.x + threadIdx.x;
  if (i < nflags) st_u32_coh(flags + i, 0u);
  if (i < nhz32) st_u32_coh(hz32 + i, 0u);
}

// ---------------- fp32 -> bf16 converts ----------------
__global__ void cvt_f32_bf16(const float* __restrict__ in,
                             unsigned short* __restrict__ out, int n4) {
  int i = blockIdx.x * blockDim.x + threadIdx.x;
  if (i >= n4) return;
  float4 v = ((const float4*)in)[i];
  ushort4 o;
  o.x = f2bf(v.x); o.y = f2bf(v.y); o.z = f2bf(v.z); o.w = f2bf(v.w);
  ((ushort4*)out)[i] = o;
}

// x [B][S][I] fp32 -> xbf [S][B][I] bf16 (time-major for per-step locality)
__global__ void cvt_x_t(const float* __restrict__ in,
                        unsigned short* __restrict__ out, int n4) {
  int i4 = blockIdx.x * blockDim.x + threadIdx.x;
  if (i4 >= n4) return;
  int d = i4 * 4;
  int i = d & (kH - 1);
  int rem = d / kH;
  int b = rem & (kB - 1);
  int s = rem / kB;
  float4 v = *(const float4*)(in + ((size_t)b * kS + s) * kH + i);
  ushort4 o;
  o.x = f2bf(v.x); o.y = f2bf(v.y); o.z = f2bf(v.z); o.w = f2bf(v.w);
  *(ushort4*)(out + (size_t)d) = o;
}

// ---------------- fused persistent 2-layer GRU ----------------
// blocks 0..127 = layer 0, 128..255 = layer 1. Each WG owns kUPW hidden
// units (12 gate rows) held as MFMA B-fragments in registers. h-state
// broadcast goes through IF$ via sc0sc1 loads/stores + per-WG flags.
// PLAIN launch (not cooperative): 256 blocks <= 256 CUs and one
// 256-thread/10KB-LDS block always fits a CU, so all blocks are resident
// regardless of VGPR count; no grid.sync() is used anywhere.
__launch_bounds__(256, 1)
__global__ void gru_fused(const unsigned short* __restrict__ xbf,   // [S][B][H]
                          const unsigned short* __restrict__ wih0,  // [3H][H]
                          const unsigned short* __restrict__ whh0,
                          const unsigned short* __restrict__ wih1,
                          const unsigned short* __restrict__ whh1,
                          const float* __restrict__ bih0, const float* __restrict__ bhh0,
                          const float* __restrict__ bih1, const float* __restrict__ bhh1,
                          unsigned short* __restrict__ hs0,    // [S][B][H] bf16
                          unsigned short* __restrict__ h1buf,  // [2][B][H] bf16
                          const unsigned short* __restrict__ hz,  // zeros [B][H]
                          unsigned int* __restrict__ flags0,   // [S][128]
                          unsigned int* __restrict__ flags1,   // [S][128]
                          float* __restrict__ out) {
  const int tid  = threadIdx.x;
  const int lane = tid & 63;
  const int wv   = tid >> 6;            // wave 0..3
  const int layer = blockIdx.x >> 7;
  const int wg    = blockIdx.x & (kNWGL - 1);
  const int j0    = wg * kUPW;

  const unsigned short* wih = layer ? wih1 : wih0;
  const unsigned short* whh = layer ? whh1 : whh0;
  const float* bih = layer ? bih1 : bih0;
  const float* bhh = layer ? bhh1 : bhh0;

  // ---- B-fragments (weights) in registers, loaded once ----
  bf16x8 bx[16], bh[16];
  {
    const int n = lane & 15, hi = lane >> 4;
    if (n < 12) {
      const int orig = (n >> 2) * kH + j0 + (n & 3);  // gate*512 + unit
      const unsigned short* pX = wih + (size_t)orig * kH + hi * 8;
      const unsigned short* pH = whh + (size_t)orig * kH + hi * 8;
#pragma unroll
      for (int kk = 0; kk < 16; ++kk) {
        bx[kk] = *(const bf16x8*)(pX + kk * 32);
        bh[kk] = *(const bf16x8*)(pH + kk * 32);
      }
    } else {
      bf16x8 z = {0, 0, 0, 0, 0, 0, 0, 0};
#pragma unroll
      for (int kk = 0; kk < 16; ++kk) { bx[kk] = z; bh[kk] = z; }
    }
  }

  // gate-phase assignment: thread -> (batch gb, unit gu)
  const int gb = tid & 63;
  const int gu = wv;
  const float bihr = bih[j0 + gu], bihz = bih[kH + j0 + gu], bihn = bih[2 * kH + j0 + gu];
  const float bhhr = bhh[j0 + gu], bhhz = bhh[kH + j0 + gu], bhhn = bhh[2 * kH + j0 + gu];
  float hprev = 0.0f;

  __shared__ float gxl[64][17];   // padded: kills 32-way bank conflict
  __shared__ float ghl[64][17];
  __shared__ unsigned short hl[64][4];
  __shared__ float hlf[64][4];

  const int b0   = wv * 16;             // M-tile batch base for this wave
  const int arow = b0 + (lane & 15);    // A row = batch
  const int ahi  = (lane >> 4) * 8;     // k sub-offset

  unsigned int* myflags = layer ? flags1 : flags0;

  for (int t = 0; t < kS; ++t) {
    // ---- wait for this step's inputs: per-WG flags, one per poller ----
    if (layer == 0) {
      if (t > 0 && tid < kNWGL)
        spin_flag(flags0 + (size_t)(t - 1) * kNWGL + tid);
    } else {
      if (tid < kNWGL)
        spin_flag(flags0 + (size_t)t * kNWGL + tid);
      else if (t > 0 && tid < 2 * kNWGL)
        spin_flag(flags1 + (size_t)(t - 1) * kNWGL + (tid - kNWGL));
    }
    __syncthreads();

    // ---- A-operand pointers ----
    const unsigned short* pAX;  // layer0: x[t] (cached); layer1: hs0[t] (coherent)
    if (layer == 0) pAX = xbf + ((size_t)t * kB + arow) * kH + ahi;
    else            pAX = hs0 + ((size_t)t * kB + arow) * kH + ahi;
    const unsigned short* pAH;  // h_{t-1} (coherent)
    if (t == 0)          pAH = hz + (size_t)arow * kH + ahi;
    else if (layer == 0) pAH = hs0 + ((size_t)(t - 1) * kB + arow) * kH + ahi;
    else                 pAH = h1buf + ((size_t)((t - 1) & 1) * kB + arow) * kH + ahi;

    // ---- fused GEMMs: gx = in_t @ Wihᵀ, gh = h_{t-1} @ Whhᵀ ----
    f32x4 accx = {0.f, 0.f, 0.f, 0.f};
    f32x4 acch = {0.f, 0.f, 0.f, 0.f};
    bf16x8 ah[16];
    coh_issue16(pAH, ah);
    if (layer == 0) {
      wait_vm0();
#pragma unroll
      for (int kk = 0; kk < 16; ++kk) {
        bf16x8 ax = *(const bf16x8*)(pAX + kk * 32);  // L2-warm cached load
        accx = __builtin_amdgcn_mfma_f32_16x16x32_bf16(ax, bx[kk], accx, 0, 0, 0);
        acch = __builtin_amdgcn_mfma_f32_16x16x32_bf16(ah[kk], bh[kk], acch, 0, 0, 0);
      }
    } else {
      bf16x8 axv[16];
      coh_issue16(pAX, axv);
      wait_vm0();
#pragma unroll
      for (int kk = 0; kk < 16; ++kk) {
        accx = __builtin_amdgcn_mfma_f32_16x16x32_bf16(axv[kk], bx[kk], accx, 0, 0, 0);
        acch = __builtin_amdgcn_mfma_f32_16x16x32_bf16(ah[kk], bh[kk], acch, 0, 0, 0);
      }
    }

    // ---- exchange via LDS: C[m][n] -> [batch][gate-row] ----
    {
      const int n = lane & 15, mb = b0 + (lane >> 4) * 4;
#pragma unroll
      for (int r = 0; r < 4; ++r) {
        gxl[mb + r][n] = accx[r];
        ghl[mb + r][n] = acch[r];
      }
    }
    __syncthreads();

    // ---- gate math (fp32) ----
    {
      const float xr = gxl[gb][gu]     + bihr;
      const float xz = gxl[gb][4 + gu] + bihz;
      const float xn = gxl[gb][8 + gu] + bihn;
      const float hr = ghl[gb][gu]     + bhhr;
      const float hzv = ghl[gb][4 + gu] + bhhz;
      const float hn = ghl[gb][8 + gu] + bhhn;
      const float r = 1.0f / (1.0f + __expf(-(xr + hr)));
      const float z = 1.0f / (1.0f + __expf(-(xz + hzv)));
      const float nn = tanhf(xn + r * hn);
      const float hnew = (1.0f - z) * nn + z * hprev;
      hprev = hnew;
      hl[gb][gu] = f2bf(hnew);
      hlf[gb][gu] = hnew;
      if (t == kS - 1)  // h_n epilogue
        out[(size_t)kB * kS * kH + (size_t)layer * kB * kH + (size_t)gb * kH + j0 + gu] = hnew;
    }
    __syncthreads();

    // ---- publish h coherently (wave 0), then release flag (same wave) ----
    if (tid < 64) {
      unsigned long long pk = *(const unsigned long long*)&hl[tid][0];
      if (layer == 0) {
        st_u64_coh(hs0 + ((size_t)t * kB + tid) * kH + j0, pk);
      } else {
        st_u64_coh(h1buf + ((size_t)(t & 1) * kB + tid) * kH + j0, pk);
        float4 o4 = *(const float4*)&hlf[tid][0];
        *(float4*)(out + ((size_t)tid * kS + t) * kH + j0) = o4;  // [b][t][h]
      }
    }
    if (tid == 0)
      st_flag_release(myflags + (size_t)t * kNWGL + wg, 1u);
    // wave 0's vmcnt(0) inside st_flag_release orders publish->flag;
    // other waves' next-step progress is gated by flags anyway.
    __syncthreads();
  }
}

extern "C" void kernel_launch(void* const* d_in, const int* in_sizes, int n_in,
                              void* d_out, int out_size, void* d_ws, size_t ws_size,
                              hipStream_t stream) {
  const float* x     = (const float*)d_in[0];
  const float* w_ih0 = (const float*)d_in[1];
  const float* w_hh0 = (const float*)d_in[2];
  const float* b_ih0 = (const float*)d_in[3];
  const float* b_hh0 = (const float*)d_in[4];
  const float* w_ih1 = (const float*)d_in[5];
  const float* w_hh1 = (const float*)d_in[6];
  const float* b_ih1 = (const float*)d_in[7];
  const float* b_hh1 = (const float*)d_in[8];
  float* out = (float*)d_out;

  // ---- workspace layout (ushort elements unless noted) ----
  unsigned short* ws = (unsigned short*)d_ws;
  const size_t nX = (size_t)kB * kS * kH;   // 33,554,432
  const size_t nW = (size_t)3 * kH * kH;    // 786,432
  unsigned short* xbf   = ws;
  unsigned short* wih0b = xbf + nX;
  unsigned short* whh0b = wih0b + nW;
  unsigned short* wih1b = whh0b + nW;
  unsigned short* whh1b = wih1b + nW;
  unsigned short* hs0   = whh1b + nW;             // nX elems
  unsigned short* h1buf = hs0 + nX;               // 2*B*H
  unsigned short* hz    = h1buf + 2 * kB * kH;    // B*H
  unsigned int*   flags0 = (unsigned int*)(hz + kB * kH);  // S*128
  unsigned int*   flags1 = flags0 + (size_t)kS * kNWGL;    // S*128

  // coherent zero-init of flags + h0 (deterministic per launch)
  {
    int nflags = 2 * kS * kNWGL;          // 262144
    int nhz32  = kB * kH / 2;             // 16384 (uint views of bf16 pairs)
    init_coh<<<(nflags + 255) / 256, 256, 0, stream>>>(flags0, nflags,
                                                       (unsigned int*)hz, nhz32);
  }

  // converts
  {
    int n4 = (int)(nX / 4);
    cvt_x_t<<<n4 / 256, 256, 0, stream>>>(x, xbf, n4);
    int w4 = (int)(nW / 4);
    cvt_f32_bf16<<<w4 / 256, 256, 0, stream>>>(w_ih0, wih0b, w4);
    cvt_f32_bf16<<<w4 / 256, 256, 0, stream>>>(w_hh0, whh0b, w4);
    cvt_f32_bf16<<<w4 / 256, 256, 0, stream>>>(w_ih1, wih1b, w4);
    cvt_f32_bf16<<<w4 / 256, 256, 0, stream>>>(w_hh1, whh1b, w4);
  }

  // fused persistent GRU — plain launch (co-residency guaranteed: 256 blocks
  // on 256 CUs, 1 block always fits a CU; no grid.sync used)
  gru_fused<<<dim3(2 * kNWGL), dim3(256), 0, stream>>>(
      xbf, wih0b, whh0b, wih1b, whh1b,
      b_ih0, b_hh0, b_ih1, b_hh1,
      hs0, h1buf, hz, flags0, flags1, out);
}

// Round 7
// 7831.939 us; speedup vs baseline: 2.8704x; 1.2745x over previous
//
#include <hip/hip_runtime.h>
#include <hip/hip_bf16.h>
#include <cstddef>

typedef __attribute__((ext_vector_type(8))) short bf16x8;
typedef __attribute__((ext_vector_type(4))) float f32x4;
typedef __attribute__((ext_vector_type(4))) unsigned int u32x4;

constexpr int kB = 64;      // batch
constexpr int kS = 1024;    // seq len
constexpr int kH = 512;     // hidden (== input size)
constexpr int kNWGL = 128;  // workgroups per layer
constexpr int kUPW = 4;     // hidden units per workgroup (12 gate rows)
constexpr int kNC = 8;      // sub-counters per step
constexpr unsigned kWant = kNWGL / kNC;  // 16 producers per sub-counter
constexpr int kSpinCap = 1 << 16;        // fail-fast, ~10ms worst per wait

__device__ __forceinline__ unsigned short f2bf(float f) {
  unsigned int u = __float_as_uint(f);
  u += 0x7FFFu + ((u >> 16) & 1u);   // round-to-nearest-even
  return (unsigned short)(u >> 16);
}

// ---------------- coherent (IF$-level) access helpers ----------------
// sc0 sc1 on load/store = system-scope: bypass L1 + non-coherent XCD L2,
// hit the Infinity-Cache coherence point directly. No wbl2/inv fences needed.

__device__ __forceinline__ void st_u32_coh(unsigned int* p, unsigned int v) {
  asm volatile("global_store_dword %0, %1, off sc0 sc1" ::"v"(p), "v"(v)
               : "memory");
}

__device__ __forceinline__ void st_u64_coh(void* p, unsigned long long v) {
  asm volatile("global_store_dwordx2 %0, %1, off sc0 sc1" ::"v"(p), "v"(v)
               : "memory");
}

// one coherent 16B load at a literal byte offset from base p
#define COH_LD16(dst, p, OFF)                                             \
  asm volatile("global_load_dwordx4 %0, %1, off offset:" #OFF " sc0 sc1"  \
               : "=v"(dst) : "v"(p) : "memory")

// issue 16 coherent 16B loads (one 512-elem bf16 row as MFMA A-fragments)
__device__ __forceinline__ void coh_issue16(const unsigned short* p, bf16x8* d) {
  COH_LD16(d[0],  p, 0);
  COH_LD16(d[1],  p, 64);
  COH_LD16(d[2],  p, 128);
  COH_LD16(d[3],  p, 192);
  COH_LD16(d[4],  p, 256);
  COH_LD16(d[5],  p, 320);
  COH_LD16(d[6],  p, 384);
  COH_LD16(d[7],  p, 448);
  COH_LD16(d[8],  p, 512);
  COH_LD16(d[9],  p, 576);
  COH_LD16(d[10], p, 640);
  COH_LD16(d[11], p, 704);
  COH_LD16(d[12], p, 768);
  COH_LD16(d[13], p, 832);
  COH_LD16(d[14], p, 896);
  COH_LD16(d[15], p, 960);
}

__device__ __forceinline__ void wait_vm0(void) {
  asm volatile("s_waitcnt vmcnt(0)" ::: "memory");
  __builtin_amdgcn_sched_barrier(0);  // rule #18: stop MFMA hoisting past wait
}

// single-thread poll of 8 contiguous sub-counters (32B) until all == kWant.
// Dependent loads self-throttle at ~1 poll per IF$ round trip.
__device__ __forceinline__ int poll8(const unsigned int* p) {
  for (int i = 0; i < kSpinCap; ++i) {
    u32x4 a, b;
    asm volatile(
        "global_load_dwordx4 %0, %2, off sc0 sc1\n\t"
        "global_load_dwordx4 %1, %2, off offset:16 sc0 sc1\n\t"
        "s_waitcnt vmcnt(0)"
        : "=v"(a), "=v"(b) : "v"(p) : "memory");
    if (a[0] == kWant && a[1] == kWant && a[2] == kWant && a[3] == kWant &&
        b[0] == kWant && b[1] == kWant && b[2] == kWant && b[3] == kWant)
      return 1;
  }
  return 0;
}

// ---------------- init: coherent zeros (h0 zeros + counters) ----------------
__global__ void init_coh(unsigned int* __restrict__ zbase, int n) {
  int i = blockIdx.x * blockDim.x + threadIdx.x;
  if (i < n) st_u32_coh(zbase + i, 0u);
}

// ---------------- fp32 -> bf16 converts ----------------
__global__ void cvt_f32_bf16(const float* __restrict__ in,
                             unsigned short* __restrict__ out, int n4) {
  int i = blockIdx.x * blockDim.x + threadIdx.x;
  if (i >= n4) return;
  float4 v = ((const float4*)in)[i];
  ushort4 o;
  o.x = f2bf(v.x); o.y = f2bf(v.y); o.z = f2bf(v.z); o.w = f2bf(v.w);
  ((ushort4*)out)[i] = o;
}

// x [B][S][I] fp32 -> xbf [S][B][I] bf16 (time-major for per-step locality)
__global__ void cvt_x_t(const float* __restrict__ in,
                        unsigned short* __restrict__ out, int n4) {
  int i4 = blockIdx.x * blockDim.x + threadIdx.x;
  if (i4 >= n4) return;
  int d = i4 * 4;
  int i = d & (kH - 1);
  int rem = d / kH;
  int b = rem & (kB - 1);
  int s = rem / kB;
  float4 v = *(const float4*)(in + ((size_t)b * kS + s) * kH + i);
  ushort4 o;
  o.x = f2bf(v.x); o.y = f2bf(v.y); o.z = f2bf(v.z); o.w = f2bf(v.w);
  *(ushort4*)(out + (size_t)d) = o;
}

// ---------------- fused persistent 2-layer GRU ----------------
// blocks 0..127 = layer 0, 128..255 = layer 1. Each WG owns kUPW hidden
// units (12 gate rows) held as MFMA B-fragments in registers. h-state
// broadcast via IF$ (sc0sc1); step completion via 8 agent-scope sub-counters
// polled by ONE thread per dependency (poll-congestion fix vs R5).
__launch_bounds__(256, 1)
__global__ void gru_fused(const unsigned short* __restrict__ xbf,   // [S][B][H]
                          const unsigned short* __restrict__ wih0,  // [3H][H]
                          const unsigned short* __restrict__ whh0,
                          const unsigned short* __restrict__ wih1,
                          const unsigned short* __restrict__ whh1,
                          const float* __restrict__ bih0, const float* __restrict__ bhh0,
                          const float* __restrict__ bih1, const float* __restrict__ bhh1,
                          unsigned short* __restrict__ hs0,    // [S][B][H] bf16
                          unsigned short* __restrict__ h1buf,  // [2][B][H] bf16
                          const unsigned short* __restrict__ hz,  // zeros [B][H]
                          unsigned int* __restrict__ cnt0,     // [S][8]
                          unsigned int* __restrict__ cnt1,     // [S][8]
                          float* __restrict__ out) {
  const int tid  = threadIdx.x;
  const int lane = tid & 63;
  const int wv   = tid >> 6;            // wave 0..3
  const int layer = blockIdx.x >> 7;
  const int wg    = blockIdx.x & (kNWGL - 1);
  const int j0    = wg * kUPW;

  const unsigned short* wih = layer ? wih1 : wih0;
  const unsigned short* whh = layer ? whh1 : whh0;
  const float* bih = layer ? bih1 : bih0;
  const float* bhh = layer ? bhh1 : bhh0;

  // ---- B-fragments (weights) in registers, loaded once ----
  bf16x8 bx[16], bh[16];
  {
    const int n = lane & 15, hi = lane >> 4;
    if (n < 12) {
      const int orig = (n >> 2) * kH + j0 + (n & 3);  // gate*512 + unit
      const unsigned short* pX = wih + (size_t)orig * kH + hi * 8;
      const unsigned short* pH = whh + (size_t)orig * kH + hi * 8;
#pragma unroll
      for (int kk = 0; kk < 16; ++kk) {
        bx[kk] = *(const bf16x8*)(pX + kk * 32);
        bh[kk] = *(const bf16x8*)(pH + kk * 32);
      }
    } else {
      bf16x8 z = {0, 0, 0, 0, 0, 0, 0, 0};
#pragma unroll
      for (int kk = 0; kk < 16; ++kk) { bx[kk] = z; bh[kk] = z; }
    }
  }

  // gate-phase assignment: thread -> (batch gb, unit gu)
  const int gb = tid & 63;
  const int gu = wv;
  const float bihr = bih[j0 + gu], bihz = bih[kH + j0 + gu], bihn = bih[2 * kH + j0 + gu];
  const float bhhr = bhh[j0 + gu], bhhz = bhh[kH + j0 + gu], bhhn = bhh[2 * kH + j0 + gu];
  float hprev = 0.0f;

  __shared__ float gxl[64][17];   // padded: kills 32-way bank conflict
  __shared__ float ghl[64][17];
  __shared__ unsigned short hl[64][4];
  __shared__ float hlf[64][4];

  const int b0   = wv * 16;             // M-tile batch base for this wave
  const int arow = b0 + (lane & 15);    // A row = batch
  const int ahi  = (lane >> 4) * 8;     // k sub-offset

  unsigned int* mycnt = layer ? cnt1 : cnt0;

  for (int t = 0; t < kS; ++t) {
    // ---- layer 0: input GEMM BEFORE the wait (x is L2-cached, flag-free) ----
    f32x4 accx = {0.f, 0.f, 0.f, 0.f};
    if (layer == 0) {
      const unsigned short* pAX = xbf + ((size_t)t * kB + arow) * kH + ahi;
#pragma unroll
      for (int kk = 0; kk < 16; ++kk) {
        bf16x8 ax = *(const bf16x8*)(pAX + kk * 32);
        accx = __builtin_amdgcn_mfma_f32_16x16x32_bf16(ax, bx[kk], accx, 0, 0, 0);
      }
    }

    // ---- wait: single poller per dependency, everyone else at barrier ----
    int ok = 1;
    if (layer == 0) {
      if (t > 0 && tid == 0) ok = poll8(cnt0 + (size_t)(t - 1) * kNC);
    } else {
      if (tid == 0) ok = poll8(cnt0 + (size_t)t * kNC);
      else if (t > 0 && tid == 64) ok = poll8(cnt1 + (size_t)(t - 1) * kNC);
    }
    if (!__syncthreads_and(ok)) break;  // fail-fast (protocol fault)

    // ---- A-operand pointers ----
    const unsigned short* pAH;  // h_{t-1} (coherent)
    if (t == 0)          pAH = hz + (size_t)arow * kH + ahi;
    else if (layer == 0) pAH = hs0 + ((size_t)(t - 1) * kB + arow) * kH + ahi;
    else                 pAH = h1buf + ((size_t)((t - 1) & 1) * kB + arow) * kH + ahi;

    f32x4 acch = {0.f, 0.f, 0.f, 0.f};
    bf16x8 ah[16];
    coh_issue16(pAH, ah);
    if (layer == 0) {
      wait_vm0();
#pragma unroll
      for (int kk = 0; kk < 16; ++kk)
        acch = __builtin_amdgcn_mfma_f32_16x16x32_bf16(ah[kk], bh[kk], acch, 0, 0, 0);
    } else {
      bf16x8 axv[16];
      coh_issue16(hs0 + ((size_t)t * kB + arow) * kH + ahi, axv);
      wait_vm0();
#pragma unroll
      for (int kk = 0; kk < 16; ++kk) {
        accx = __builtin_amdgcn_mfma_f32_16x16x32_bf16(axv[kk], bx[kk], accx, 0, 0, 0);
        acch = __builtin_amdgcn_mfma_f32_16x16x32_bf16(ah[kk], bh[kk], acch, 0, 0, 0);
      }
    }

    // ---- exchange via LDS: C[m][n] -> [batch][gate-row] ----
    {
      const int n = lane & 15, mb = b0 + (lane >> 4) * 4;
#pragma unroll
      for (int r = 0; r < 4; ++r) {
        gxl[mb + r][n] = accx[r];
        ghl[mb + r][n] = acch[r];
      }
    }
    __syncthreads();

    // ---- gate math (fp32) ----
    {
      const float xr = gxl[gb][gu]     + bihr;
      const float xz = gxl[gb][4 + gu] + bihz;
      const float xn = gxl[gb][8 + gu] + bihn;
      const float hr = ghl[gb][gu]     + bhhr;
      const float hzv = ghl[gb][4 + gu] + bhhz;
      const float hn = ghl[gb][8 + gu] + bhhn;
      const float r = 1.0f / (1.0f + __expf(-(xr + hr)));
      const float z = 1.0f / (1.0f + __expf(-(xz + hzv)));
      const float nn = tanhf(xn + r * hn);
      const float hnew = (1.0f - z) * nn + z * hprev;
      hprev = hnew;
      hl[gb][gu] = f2bf(hnew);
      hlf[gb][gu] = hnew;
      if (t == kS - 1)  // h_n epilogue
        out[(size_t)kB * kS * kH + (size_t)layer * kB * kH + (size_t)gb * kH + j0 + gu] = hnew;
    }
    __syncthreads();

    // ---- publish h coherently (wave 0), then counter add (same wave) ----
    if (tid < 64) {
      unsigned long long pk = *(const unsigned long long*)&hl[tid][0];
      if (layer == 0) {
        st_u64_coh(hs0 + ((size_t)t * kB + tid) * kH + j0, pk);
      } else {
        st_u64_coh(h1buf + ((size_t)(t & 1) * kB + tid) * kH + j0, pk);
        float4 o4 = *(const float4*)&hlf[tid][0];
        *(float4*)(out + ((size_t)tid * kS + t) * kH + j0) = o4;  // [b][t][h]
      }
    }
    if (tid == 0) {
      // all publishes are wave-0 stores: drain this wave, then signal
      asm volatile("s_waitcnt vmcnt(0)" ::: "memory");
      __hip_atomic_fetch_add(mycnt + (size_t)t * kNC + (wg & (kNC - 1)), 1u,
                             __ATOMIC_RELAXED, __HIP_MEMORY_SCOPE_AGENT);
    }
    __syncthreads();
  }
}

extern "C" void kernel_launch(void* const* d_in, const int* in_sizes, int n_in,
                              void* d_out, int out_size, void* d_ws, size_t ws_size,
                              hipStream_t stream) {
  const float* x     = (const float*)d_in[0];
  const float* w_ih0 = (const float*)d_in[1];
  const float* w_hh0 = (const float*)d_in[2];
  const float* b_ih0 = (const float*)d_in[3];
  const float* b_hh0 = (const float*)d_in[4];
  const float* w_ih1 = (const float*)d_in[5];
  const float* w_hh1 = (const float*)d_in[6];
  const float* b_ih1 = (const float*)d_in[7];
  const float* b_hh1 = (const float*)d_in[8];
  float* out = (float*)d_out;

  // ---- workspace layout (ushort elements unless noted) ----
  unsigned short* ws = (unsigned short*)d_ws;
  const size_t nX = (size_t)kB * kS * kH;   // 33,554,432
  const size_t nW = (size_t)3 * kH * kH;    // 786,432
  unsigned short* xbf   = ws;
  unsigned short* wih0b = xbf + nX;
  unsigned short* whh0b = wih0b + nW;
  unsigned short* wih1b = whh0b + nW;
  unsigned short* whh1b = wih1b + nW;
  unsigned short* hs0   = whh1b + nW;             // nX elems
  unsigned short* h1buf = hs0 + nX;               // 2*B*H
  unsigned short* hz    = h1buf + 2 * kB * kH;    // B*H
  unsigned int*   cnt0  = (unsigned int*)(hz + kB * kH);  // S*8
  unsigned int*   cnt1  = cnt0 + (size_t)kS * kNC;        // S*8

  // coherent zero-init of hz + counters (contiguous), each launch
  {
    int nz = kB * kH / 2 + 2 * kS * kNC;   // 16384 + 16384 u32
    init_coh<<<(nz + 255) / 256, 256, 0, stream>>>((unsigned int*)hz, nz);
  }

  // converts
  {
    int n4 = (int)(nX / 4);
    cvt_x_t<<<n4 / 256, 256, 0, stream>>>(x, xbf, n4);
    int w4 = (int)(nW / 4);
    cvt_f32_bf16<<<w4 / 256, 256, 0, stream>>>(w_ih0, wih0b, w4);
    cvt_f32_bf16<<<w4 / 256, 256, 0, stream>>>(w_hh0, whh0b, w4);
    cvt_f32_bf16<<<w4 / 256, 256, 0, stream>>>(w_hh1 ? w_hh0 : w_hh0, whh0b, 0);  // no-op guard
    cvt_f32_bf16<<<w4 / 256, 256, 0, stream>>>(w_ih1, wih1b, w4);
    cvt_f32_bf16<<<w4 / 256, 256, 0, stream>>>(w_hh1, whh1b, w4);
  }

  // fused persistent GRU — plain launch (co-residency guaranteed: 256 blocks
  // on 256 CUs, 1 block always fits a CU; no grid.sync used)
  gru_fused<<<dim3(2 * kNWGL), dim3(256), 0, stream>>>(
      xbf, wih0b, whh0b, wih1b, whh1b,
      b_ih0, b_hh0, b_ih1, b_hh1,
      hs0, h1buf, hz, cnt0, cnt1, out);
}